// Round 1
// baseline (466.830 us; speedup 1.0000x reference)
//
#include <hip/hip_runtime.h>

// Problem shape (fixed by setup_inputs): left/right [B,C,H,W] fp32,
// out volume [B,C,D,H,W] fp32, out[b,c,d,y,x] = left[b,c,y,x] - right[b,c,y,x-d] (x>=d else 0)
#define BB 2
#define CC 32
#define HH 96
#define WW 320
#define DD 48
#define W4 (WW / 4)   // 80 float4 per row

// One thread per output float4. Ordering of flat index: (bc, d, y, x4) ->
// matches output layout exactly, so the store index == thread index (fully
// coalesced streaming float4 stores). Left load is an aligned float4; right
// loads are 4 scalars at the shifted column (unaligned in general), which hit
// L1/L2 — inputs are only 15.7 MB total and each right row is reused 48x.
__global__ __launch_bounds__(256) void diffvol_kernel(
        const float* __restrict__ left,
        const float* __restrict__ right,
        float* __restrict__ out) {
    int idx = blockIdx.x * blockDim.x + threadIdx.x;   // float4 index, < 23,592,960

    int x4 = idx % W4;
    int t  = idx / W4;
    int y  = t % HH;
    t /= HH;
    int d  = t % DD;
    int bc = t / DD;                                   // fused b*C + c, 0..63

    int base = (bc * HH + y) * WW;                     // row base in left/right
    int x = x4 * 4;

    const float4 lv = *(const float4*)(left + base + x);
    const float* rrow = right + base;

    float4 o;
    o.x = (x + 0 >= d) ? lv.x - rrow[x + 0 - d] : 0.0f;
    o.y = (x + 1 >= d) ? lv.y - rrow[x + 1 - d] : 0.0f;
    o.z = (x + 2 >= d) ? lv.z - rrow[x + 2 - d] : 0.0f;
    o.w = (x + 3 >= d) ? lv.w - rrow[x + 3 - d] : 0.0f;

    ((float4*)out)[idx] = o;
}

extern "C" void kernel_launch(void* const* d_in, const int* in_sizes, int n_in,
                              void* d_out, int out_size, void* d_ws, size_t ws_size,
                              hipStream_t stream) {
    const float* left  = (const float*)d_in[0];
    const float* right = (const float*)d_in[1];
    float* out = (float*)d_out;

    const int total4 = BB * CC * DD * HH * W4;         // 23,592,960
    const int block = 256;
    const int grid = total4 / block;                   // 92,160 (exact)
    diffvol_kernel<<<grid, block, 0, stream>>>(left, right, out);
}

// Round 2
// 388.433 us; speedup vs baseline: 1.2018x; 1.2018x over previous
//
#include <hip/hip_runtime.h>

// Problem shape (fixed by setup_inputs): left/right [B,C,H,W] fp32,
// out volume [B,C,D,H,W] fp32:
//   out[b,c,d,y,x] = left[b,c,y,x] - right[b,c,y,x-d]  (x>=d, else 0)
#define BB 2
#define CC 32
#define HH 96
#define WW 320
#define DD 48

// One block per (bc, y) row: 320 threads (5 waves), thread t owns column x=t.
// Right row staged in LDS once (stride-1 lane access -> 2-way bank aliasing,
// free on gfx950); left value lives in a register. The d-loop then emits 48
// perfectly coalesced contiguous stores per thread, reusing the LDS row for
// every shift. Global reads: 2 x 1280 B per block (one clean pass over each
// input = 15.7 MB total); writes: 61,440 B per block (377 MB stream).
// Only wave 0 (t < 64) can hit the x < d boundary since d <= 47, so the
// validity predicate is hoisted out of the other 4 waves entirely.
__global__ __launch_bounds__(320) void diffvol_kernel(
        const float* __restrict__ left,
        const float* __restrict__ right,
        float* __restrict__ out) {
    __shared__ float rrow[WW];

    const int tid = threadIdx.x;              // 0..319 == column x
    const int blk = blockIdx.x;               // 0..6143
    const int y   = blk % HH;
    const int bc  = blk / HH;                 // fused b*C + c

    const int base = (bc * HH + y) * WW;
    const float lv = left[base + tid];
    rrow[tid] = right[base + tid];
    __syncthreads();

    // out offset for (bc, d, y, x=tid): ((bc*DD + d)*HH + y)*WW + tid
    float* o = out + ((bc * DD) * HH + y) * WW + tid;
    const int dstride = HH * WW;              // 30720 floats between d-slices

    if (tid >= 64) {
        // d <= 47 < 64 <= tid: always valid, no predicate needed.
        #pragma unroll
        for (int d = 0; d < DD; ++d) {
            o[d * dstride] = lv - rrow[tid - d];
        }
    } else {
        #pragma unroll
        for (int d = 0; d < DD; ++d) {
            o[d * dstride] = (tid >= d) ? lv - rrow[tid - d] : 0.0f;
        }
    }
}

extern "C" void kernel_launch(void* const* d_in, const int* in_sizes, int n_in,
                              void* d_out, int out_size, void* d_ws, size_t ws_size,
                              hipStream_t stream) {
    const float* left  = (const float*)d_in[0];
    const float* right = (const float*)d_in[1];
    float* out = (float*)d_out;

    const int grid = BB * CC * HH;            // 6144 blocks, one per row
    diffvol_kernel<<<grid, 320, 0, stream>>>(left, right, out);
}